// Round 9
// baseline (583.595 us; speedup 1.0000x reference)
//
#include <hip/hip_runtime.h>
#include <hip/hip_bf16.h>
#include <stdint.h>

// Problem constants
#define S_LEN 1024
#define B_SZ  64
#define I_SZ  512
#define H_SZ  2048
#define O_SZ  512

typedef __bf16  bf16x8 __attribute__((ext_vector_type(8)));
typedef float   f32x4  __attribute__((ext_vector_type(4)));

static __device__ __forceinline__ ushort f2bf(float f) {
  union { float f; unsigned u; } v; v.f = f;
  unsigned r = v.u + 0x7FFFu + ((v.u >> 16) & 1u);   // RNE
  return (ushort)(r >> 16);
}
static __device__ __forceinline__ float bf2f(ushort u) {
  return __builtin_bit_cast(float, (unsigned)u << 16);
}

// async global->LDS, 16B per lane: LDS dest is WAVE-UNIFORM base + lane*16
#define GLOAD_LDS16(gp, lp) \
  __builtin_amdgcn_global_load_lds( \
      (__attribute__((address_space(1))) void*)(gp), \
      (__attribute__((address_space(3))) void*)(lp), 16, 0, 0)

// ---------------------------------------------------------------- W convert (tiny)
__global__ __launch_bounds__(256) void convert_f32_bf16_kernel(
    const float4* __restrict__ in, ushort4* __restrict__ out, int n4) {
  int i = blockIdx.x * 256 + threadIdx.x;
  if (i >= n4) return;
  float4 v = in[i];
  ushort4 o; o.x = f2bf(v.x); o.y = f2bf(v.y); o.z = f2bf(v.z); o.w = f2bf(v.w);
  out[i] = o;
}

// ---------------------------------------------------------------- X convert+transpose
// X[s][b][i] fp32 -> Xbf[b][s][i] bf16. One wave per (s,b) row.
__global__ __launch_bounds__(256) void convert_x_kernel(
    const float* __restrict__ X, ushort* __restrict__ Xt) {
  const int row  = blockIdx.x * 4 + (threadIdx.x >> 6);  // s*64 + b
  const int lane = threadIdx.x & 63;
  const int s = row >> 6, b = row & 63;
  const float* src = X + (size_t)row * I_SZ + lane * 8;
  float4 v0 = *(const float4*)src;
  float4 v1 = *(const float4*)(src + 4);
  union { ushort h[8]; uint4 v; } o;
  o.h[0] = f2bf(v0.x); o.h[1] = f2bf(v0.y); o.h[2] = f2bf(v0.z); o.h[3] = f2bf(v0.w);
  o.h[4] = f2bf(v1.x); o.h[5] = f2bf(v1.y); o.h[6] = f2bf(v1.z); o.h[7] = f2bf(v1.w);
  *(uint4*)(Xt + ((size_t)b * S_LEN + s) * I_SZ + lane * 8) = o.v;
}

// ---------------------------------------------------------------- Y = bias (runs BEFORE fused)
__global__ __launch_bounds__(256) void init_y_kernel(
    const float* __restrict__ bho, float* __restrict__ Y) {
  int idx = blockIdx.x * 256 + threadIdx.x;   // 0..32767
  Y[idx] = bho[idx & (O_SZ - 1)];
}

#define SCAN16(colp, s0_) do { \
    ushort4 v0 = *(const ushort4*)&(colp)[(s0_)]; \
    ushort4 v1 = *(const ushort4*)&(colp)[(s0_) + 4]; \
    ushort4 v2 = *(const ushort4*)&(colp)[(s0_) + 8]; \
    ushort4 v3 = *(const ushort4*)&(colp)[(s0_) + 12]; \
    p = fmaf(c, fabsf(p), bf2f(v0.x)); p = fmaf(c, fabsf(p), bf2f(v0.y)); \
    p = fmaf(c, fabsf(p), bf2f(v0.z)); p = fmaf(c, fabsf(p), bf2f(v0.w)); \
    p = fmaf(c, fabsf(p), bf2f(v1.x)); p = fmaf(c, fabsf(p), bf2f(v1.y)); \
    p = fmaf(c, fabsf(p), bf2f(v1.z)); p = fmaf(c, fabsf(p), bf2f(v1.w)); \
    p = fmaf(c, fabsf(p), bf2f(v2.x)); p = fmaf(c, fabsf(p), bf2f(v2.y)); \
    p = fmaf(c, fabsf(p), bf2f(v2.z)); p = fmaf(c, fabsf(p), bf2f(v2.w)); \
    p = fmaf(c, fabsf(p), bf2f(v3.x)); p = fmaf(c, fabsf(p), bf2f(v3.y)); \
    p = fmaf(c, fabsf(p), bf2f(v3.z)); p = fmaf(c, fabsf(p), bf2f(v3.w)); \
  } while (0)

// stage K-step T (64 rows x BK=32) into wave-private LDS bufs dA/dB.
// 8 gload_lds (4 A + 4 B), each 64 lanes x 16B = 1KB = 16 rows x 64B.
// Image (R8 silicon-proven, 0 conflicts): slot s of row r holds chunk
// (s - (r>>1)) & 3; source lane map lchunk = ((l&3) - (l>>3)) & 3.
#define STAGE(dA, dB, T) do { \
    const ushort* ga_ = gA + (size_t)((T) >> 4) * (64 * I_SZ) + ((T) & 15) * 32; \
    const ushort* gb_ = gB + ((T) & 15) * 32; \
    GLOAD_LDS16(ga_,              (dA)); \
    GLOAD_LDS16(ga_ + 16 * I_SZ, (dA) + 512); \
    GLOAD_LDS16(ga_ + 32 * I_SZ, (dA) + 1024); \
    GLOAD_LDS16(ga_ + 48 * I_SZ, (dA) + 1536); \
    GLOAD_LDS16(gb_,              (dB)); \
    GLOAD_LDS16(gb_ + 16 * I_SZ, (dB) + 512); \
    GLOAD_LDS16(gb_ + 32 * I_SZ, (dB) + 1024); \
    GLOAD_LDS16(gb_ + 48 * I_SZ, (dB) + 1536); \
  } while (0)

// one K-step: stage t+1 into (NA,NB), counted vmcnt wait (retire step t's 8
// loads; t+1's stay in flight -- NO barrier ever drains them), compute from
// (CA,CB), at s-tile end epilogue+scan (wave-internal lgkm ordering only).
#define BODY(T, CA, CB, NA, NB) do { \
    const int t_ = (T); \
    if ((t_ & 15) == 0) { \
      _Pragma("unroll") \
      for (int mi_ = 0; mi_ < 4; ++mi_) \
        _Pragma("unroll") \
        for (int ni_ = 0; ni_ < 4; ++ni_) { \
          f32x4 z_ = {0.f, 0.f, 0.f, 0.f}; \
          acc[mi_][ni_] = z_; \
        } \
    } \
    if (t_ < 255) { \
      STAGE(NA, NB, t_ + 1); \
      asm volatile("s_waitcnt vmcnt(8)" ::: "memory"); \
    } else { \
      asm volatile("s_waitcnt vmcnt(0)" ::: "memory"); \
    } \
    __builtin_amdgcn_sched_barrier(0); \
    { \
      bf16x8 af_[4], bf_[4]; \
      _Pragma("unroll") \
      for (int i_ = 0; i_ < 4; ++i_) { \
        af_[i_] = *(const bf16x8*)&(CA)[arow[i_] + foff]; \
        bf_[i_] = *(const bf16x8*)&(CB)[arow[i_] + foff]; \
      } \
      __builtin_amdgcn_s_setprio(1); \
      _Pragma("unroll") \
      for (int mi_ = 0; mi_ < 4; ++mi_) \
        _Pragma("unroll") \
        for (int ni_ = 0; ni_ < 4; ++ni_) \
          acc[mi_][ni_] = __builtin_amdgcn_mfma_f32_16x16x32_bf16( \
              af_[mi_], bf_[ni_], acc[mi_][ni_], 0, 0, 0); \
      __builtin_amdgcn_s_setprio(0); \
    } \
    if ((t_ & 15) == 15) { \
      _Pragma("unroll") \
      for (int mi_ = 0; mi_ < 4; ++mi_) \
        _Pragma("unroll") \
        for (int ni_ = 0; ni_ < 4; ++ni_) { \
          ushort4 o_; \
          o_.x = f2bf(acc[mi_][ni_][0]); o_.y = f2bf(acc[mi_][ni_][1]); \
          o_.z = f2bf(acc[mi_][ni_][2]); o_.w = f2bf(acc[mi_][ni_][3]); \
          *(ushort4*)&CsU[(ni_ * 16 + ml) * 66 + mi_ * 16 + q * 4] = o_; \
        } \
      const ushort* col_ = &CsU[lane * 66]; \
      SCAN16(col_, 0); SCAN16(col_, 16); SCAN16(col_, 32); SCAN16(col_, 48); \
    } \
  } while (0)

// ---------------------------------------------------------------- fused GEMM + scan + projection
// Grid: 2048 blocks = (b, ht64) x 64 THREADS (one wave). BARRIER-FREE: all
// LDS is wave-private, so the forced vmcnt(0) drain at __syncthreads -- the
// invariant limiter of R0/R3 (235us) and R6/R8 (300us), where all 4 waves of
// a block stalled in lockstep at every K-step -- does not exist. Double-
// buffered BK=32 staging with hand-placed COUNTED vmcnt(8): step t+1's loads
// stay in flight through step t's MFMA (T4, legal without barriers). Waves
// stall independently; ~6 blocks/CU co-resident cover each other.
// LDS 24832 B: A dbuf 2x4KB @0, B dbuf 2x4KB @8192B, Cs[64][66] @16384B.
__global__ __launch_bounds__(64) void fused_gemm_scan_kernel(
    const ushort* __restrict__ Xbf,   // [64][1024][512] bf16, batch-major
    const ushort* __restrict__ Wbf,   // [2048][512] bf16
    const float* __restrict__ hh,     // [2048]
    const float* __restrict__ Who,    // [512][2048] fp32
    float* __restrict__ Y) {          // [64][512], pre-seeded with bias
  __shared__ __align__(16) ushort smem[12416];   // 24832 B -> 6 blocks/CU
  ushort* A0  = smem;             // [64][32] sigma-rotated
  ushort* A1  = smem + 2048;
  ushort* B0  = smem + 4096;
  ushort* B1  = smem + 6144;
  ushort* CsU = smem + 8192;      // [64 h][66 s]

  const int lane = threadIdx.x;   // 64 threads = 1 wave

  const int bid = blockIdx.x;
  const int xcd = bid & 7;            // XCD (bid%8 heuristic)
  const int g   = bid >> 3;           // 0..255
  const int b   = (xcd << 3) | (g & 7);  // same-b -> same XCD (Xbf L2 reuse)
  const int ht  = g >> 3;             // h-tile 0..31 (64-wide)

  const int ml = lane & 15;
  const int q  = lane >> 4;

  // staging source (sigma rotate, R8-proven): lane l covers rows
  // j*16 + (l>>2), slot l&3, global chunk ((l&3) - (l>>3)) & 3
  const int lrow   = lane >> 2;
  const int lchunk = ((lane & 3) - (lane >> 3)) & 3;
  const ushort* gA = Xbf + (size_t)b * (S_LEN * I_SZ)
                   + (size_t)lrow * I_SZ + lchunk * 8;
  const ushort* gB = Wbf + (size_t)(ht * 64 + lrow) * I_SZ + lchunk * 8;

  // fragment reads: chunk q of row r at slot (q + (r>>1)) & 3
  const int foff = ((q + (ml >> 1)) & 3) * 8;
  int arow[4];
  #pragma unroll
  for (int i = 0; i < 4; ++i) arow[i] = (i * 16 + ml) * 32;

  float c = hh[ht * 64 + lane];       // scan coefficient (one h-col per lane)
  float p = 0.0f;                     // scan state (pre-abs h)

  f32x4 acc[4][4];

  // prologue: stage step 0 (8 loads in flight)
  STAGE(A0, B0, 0);

  #pragma unroll 1
  for (int tt = 0; tt < 128; ++tt) {  // t = st*16 + kt, 256 steps total
    BODY(2 * tt,     A0, B0, A1, B1);
    BODY(2 * tt + 1, A1, B1, A0, B0);
  }

  // ---- h handoff (wave-internal; drain LDS writes before cross-lane reads)
  {
    float* hs = (float*)CsU;
    hs[lane] = fabsf(p);
    asm volatile("s_waitcnt lgkmcnt(0)" ::: "memory");
  }

  // ---- Y[b, :] += h . Who[:, ht*64 .. +64)   (Who slice is L2-resident)
  {
    const float* hs = (const float*)CsU;
    #pragma unroll
    for (int j = 0; j < 8; ++j) {
      const int o = j * 64 + lane;
      const float* wp = Who + (size_t)o * H_SZ + ht * 64;
      float y = 0.f;
      #pragma unroll 4
      for (int k = 0; k < 64; k += 4) {
        float4 hv = *(const float4*)&hs[k];   // broadcast
        float4 wv = *(const float4*)&wp[k];
        y += hv.x * wv.x + hv.y * wv.y + hv.z * wv.z + hv.w * wv.w;
      }
      atomicAdd(&Y[(size_t)b * O_SZ + o], y);
    }
  }
}

// ---------------------------------------------------------------- launch
extern "C" void kernel_launch(void* const* d_in, const int* in_sizes, int n_in,
                              void* d_out, int out_size, void* d_ws, size_t ws_size,
                              hipStream_t stream) {
  (void)in_sizes; (void)n_in; (void)out_size; (void)ws_size;
  const float* X   = (const float*)d_in[0];   // [1024][64][512]
  const float* Wih = (const float*)d_in[1];   // [2048][512]
  const float* hh  = (const float*)d_in[2];   // [2048]
  const float* Who = (const float*)d_in[3];   // [512][2048]
  const float* bho = (const float*)d_in[4];   // [512]
  float* Y = (float*)d_out;                   // [64][512]

  const size_t WBF = (size_t)H_SZ * I_SZ * 2;          // 2 MiB
  char* w = (char*)d_ws;
  ushort* Wbf = (ushort*)w;                            // 2 MiB
  ushort* Xbf = (ushort*)(w + WBF);                    // 64 MiB, [b][s][i]

  // W convert (tiny)
  {
    int n4w = (int)((size_t)H_SZ * I_SZ / 4);          // 262144
    convert_f32_bf16_kernel<<<n4w / 256, 256, 0, stream>>>(
        (const float4*)Wih, (ushort4*)Wbf, n4w);
  }

  // X convert + transpose to batch-major bf16
  convert_x_kernel<<<(S_LEN * B_SZ) / 4, 256, 0, stream>>>(X, Xbf);

  // Y <- bias (must complete before fused kernel's atomics; stream-ordered)
  init_y_kernel<<<(B_SZ * O_SZ) / 256, 256, 0, stream>>>(bho, Y);

  // fused GEMM + scan + projection (1 wave per block, barrier-free)
  fused_gemm_scan_kernel<<<2048, 64, 0, stream>>>(Xbf, Wbf, hh, Who, Y);
}